// Round 6
// baseline (415.554 us; speedup 1.0000x reference)
//
#include <hip/hip_runtime.h>

// LTC cell: out = states after 6 SDE unfolds of s += drift(s),
// drift = 6 ODE unfolds of v = (cm*v + gleak*vleak + num)/(cm + gleak + den).
//
// R5 post-mortem: VGPR_Count=64 -> compiler targeted 8 waves/SIMD and parked
// the pinned P[] in AGPRs; +4 v_accvgpr_read per SIGACC made the main pipe as
// long as the trans pipe (293 us VALU issue). Root cause both rounds: the
// allocator's occupancy heuristic. R6: pin it with amdgpu_waves_per_eu(2,2)
// (256-VGPR budget, 2 waves/SIMD — param residency needs 256 KB/block = half
// the CU register file, so 2 waves/SIMD is the ONLY residency-compatible
// occupancy; trans pipe stays saturated: 2 waves x 2048 trans-cy/iter cover
// the 8192-cy/SIMD/iter over 2 grid rounds).
// Structural stall removal: reduction split s is LANE-ENCODED (lane=(s<<4)|jlo)
// -> partials combine via __shfl_xor(16/32) IN-WAVE (no part[] LDS, no 2nd
// barrier); v double-buffered in LDS -> exactly 1 __syncthreads per ODE iter.
// Floor: 2 trans/pair (v_exp+v_rcp, 8cy each) x 1.21e9 pairs = 123 us.
// Predict 150-185 us; VGPR ~190-210; zero loop VMEM; WRITE ~1 MB.

#define LOG2E 1.4426950408889634f

constexpr int U   = 128;
constexpr int I   = 64;
constexpr int B   = 2048;
constexpr int M   = 4;        // batch elements per block (per thread)
constexpr int S   = 4;        // i-split, encoded in lane bits 4-5
constexpr int BLK = 512;      // 8 waves; (j:128) x (s:4)
constexpr int RPT = U / S;    // 32 param rows per thread (128 VGPR)
constexpr int SDE = 6, ODE = 6;

#if __has_builtin(__builtin_amdgcn_exp2f)
#define EXP2(x) __builtin_amdgcn_exp2f(x)
#else
#define EXP2(x) exp2f(x)
#endif
#if __has_builtin(__builtin_amdgcn_rcpf)
#define RCP(x) __builtin_amdgcn_rcpf(x)
#else
#define RCP(x) (1.0f / (x))
#endif

// one sigmoid-accumulate pair: P = {A=-log2e*sigma, Bc=log2e*sigma*mu, W*erev, W}
#define SIGACC(P, V, PN, PD)                                   \
  {                                                            \
    float t_ = fmaf((P).x, (V), (P).y);                        \
    float e_ = EXP2(t_);                                       \
    float r_ = RCP(1.0f + e_);                                 \
    (PN) = fmaf((P).z, r_, (PN));                              \
    (PD) = fmaf((P).w, r_, (PD));                              \
  }

__global__ __launch_bounds__(256) void pack_params(
    const float* __restrict__ mu, const float* __restrict__ sigma,
    const float* __restrict__ W, const float* __restrict__ erev,
    const float* __restrict__ smu, const float* __restrict__ ssig,
    const float* __restrict__ sW, const float* __restrict__ serev,
    float4* __restrict__ pp, float4* __restrict__ ps)
{
  int idx = blockIdx.x * 256 + threadIdx.x;
  if (idx < U * U) {
    float sg = sigma[idx];
    float w  = W[idx];
    pp[idx] = make_float4(-LOG2E * sg, LOG2E * sg * mu[idx], w * erev[idx], w);
  } else if (idx < U * U + I * U) {
    int k = idx - U * U;
    float sg = ssig[k];
    float w  = sW[k];
    ps[k] = make_float4(-LOG2E * sg, LOG2E * sg * smu[k], w * serev[k], w);
  }
}

__global__ __launch_bounds__(BLK)
__attribute__((amdgpu_waves_per_eu(2, 2)))   // pin allocator: 256-VGPR budget
void ltc_kernel(
    const float4* __restrict__ pp, const float4* __restrict__ ps,
    const float* __restrict__ inputs, const float* __restrict__ states,
    const float* __restrict__ iw, const float* __restrict__ ibias,
    const float* __restrict__ vleak, const float* __restrict__ gleak,
    const float* __restrict__ cmt, float* __restrict__ out)
{
  __shared__ __align__(16) float4 v4[2][M][U / 4];  // double-buffered v, 4 KB
  __shared__ __align__(16) float x_lds[M][I];       // 1 KB

  const int tid = threadIdx.x;
  const int jlo = tid & 15;
  const int s   = (tid >> 4) & 3;          // i-split id, lane bits 4-5
  const int j   = ((tid >> 6) << 4) | jlo; // output unit (same for all s-replicas)
  const int b0  = blockIdx.x * M;

  const float cm = cmt[j];
  const float gl = gleak[j];
  const float gv = gl * vleak[j];
  const float cg = cm + gl;

  // ---- this thread's param rows i in [s*32, s*32+32) -> 32 float4 = 128 VGPR ----
  float4 P[RPT];
#pragma unroll
  for (int k = 0; k < RPT; ++k) P[k] = pp[(s * RPT + k) * U + j];

  // stage mapped input x = in*w + b into LDS
  if (tid < M * I) {
    const int m = tid >> 6, i = tid & (I - 1);
    x_lds[m][i] = inputs[(b0 + m) * I + i] * iw[i] + ibias[i];
  }
  __syncthreads();

  // ---- sensory terms (constant across unfolds); i in [s*16, s*16+16) ----
  float wns[M], wds[M];
  {
    float pn[M], pd[M];
#pragma unroll
    for (int m = 0; m < M; ++m) { pn[m] = 0.f; pd[m] = 0.f; }
#pragma unroll
    for (int q = 0; q < 4; ++q) {
      const int i = s * 16 + q * 4;
      const float4 p0 = ps[(i + 0) * U + j];
      const float4 p1 = ps[(i + 1) * U + j];
      const float4 p2 = ps[(i + 2) * U + j];
      const float4 p3 = ps[(i + 3) * U + j];
#pragma unroll
      for (int m = 0; m < M; ++m) {
        const float4 xv = *reinterpret_cast<const float4*>(&x_lds[m][i]);
        SIGACC(p0, xv.x, pn[m], pd[m]);
        SIGACC(p1, xv.y, pn[m], pd[m]);
        SIGACC(p2, xv.z, pn[m], pd[m]);
        SIGACC(p3, xv.w, pn[m], pd[m]);
      }
    }
    // in-wave combine across the 4 s-replicas (lane bits 4-5)
#pragma unroll
    for (int m = 0; m < M; ++m) {
      float n = pn[m], d = pd[m];
      n += __shfl_xor(n, 16); n += __shfl_xor(n, 32);
      d += __shfl_xor(d, 16); d += __shfl_xor(d, 32);
      wns[m] = n; wds[m] = d;
    }
  }

  // keep-alive pin: P must stay materialized (not re-loaded) past this point
#pragma unroll
  for (int k = 0; k < RPT; ++k)
    asm volatile("" : "+v"(P[k].x), "+v"(P[k].y), "+v"(P[k].z), "+v"(P[k].w));

  float sv[M];
#pragma unroll
  for (int m = 0; m < M; ++m) sv[m] = states[(b0 + m) * U + j];

  int buf = 0;
  float vj[M];
  for (int sde = 0; sde < SDE; ++sde) {
#pragma unroll
    for (int m = 0; m < M; ++m) vj[m] = sv[m];
    buf ^= 1;
    if (s == 0) {   // lanes 0-15 of each wave publish their 16 consecutive j's
#pragma unroll
      for (int m = 0; m < M; ++m)
        reinterpret_cast<float*>(&v4[buf][m][0])[j] = sv[m];
    }
    __syncthreads();

    for (int ode = 0; ode < ODE; ++ode) {
      float pn[M], pd[M];
#pragma unroll
      for (int m = 0; m < M; ++m) { pn[m] = 0.f; pd[m] = 0.f; }
      // main i-sweep: params from registers, v from LDS (4 addrs/wave; 4-way
      // bank alias hidden under the trans pipe), ZERO global memory.
#pragma unroll
      for (int q = 0; q < 8; ++q) {
#pragma unroll
        for (int m = 0; m < M; ++m) {
          const float4 vv = v4[buf][m][s * 8 + q];
          SIGACC(P[q * 4 + 0], vv.x, pn[m], pd[m]);
          SIGACC(P[q * 4 + 1], vv.y, pn[m], pd[m]);
          SIGACC(P[q * 4 + 2], vv.z, pn[m], pd[m]);
          SIGACC(P[q * 4 + 3], vv.w, pn[m], pd[m]);
        }
      }
      // in-wave reduction + v-update (computed redundantly by all s-replicas)
#pragma unroll
      for (int m = 0; m < M; ++m) {
        float n = pn[m], d = pd[m];
        n += __shfl_xor(n, 16); n += __shfl_xor(n, 32);
        d += __shfl_xor(d, 16); d += __shfl_xor(d, 32);
        n += wns[m]; d += wds[m];
        const float den = cg + d;
        float r = RCP(den);
        r = r * (2.0f - den * r);            // one Newton step on the feedback path
        vj[m] = (fmaf(cm, vj[m], gv) + n) * r;
      }
      buf ^= 1;                               // write the OTHER buffer (WAR-safe)
      if (s == 0) {
#pragma unroll
        for (int m = 0; m < M; ++m)
          reinterpret_cast<float*>(&v4[buf][m][0])[j] = vj[m];
      }
      __syncthreads();                        // the ONLY barrier per ODE iter
    }
#pragma unroll
    for (int m = 0; m < M; ++m) sv[m] += vj[m];
  }

  if (s == 0) {
#pragma unroll
    for (int m = 0; m < M; ++m) out[(b0 + m) * U + j] = sv[m];
  }
}

extern "C" void kernel_launch(void* const* d_in, const int* in_sizes, int n_in,
                              void* d_out, int out_size, void* d_ws, size_t ws_size,
                              hipStream_t stream) {
  const float* inputs = (const float*)d_in[0];
  const float* states = (const float*)d_in[1];
  const float* iw     = (const float*)d_in[2];
  const float* ibias  = (const float*)d_in[3];
  const float* smu    = (const float*)d_in[4];
  const float* ssig   = (const float*)d_in[5];
  const float* sW     = (const float*)d_in[6];
  const float* serev  = (const float*)d_in[7];
  const float* mu     = (const float*)d_in[8];
  const float* sigma  = (const float*)d_in[9];
  const float* W      = (const float*)d_in[10];
  const float* erev   = (const float*)d_in[11];
  const float* vleak  = (const float*)d_in[12];
  const float* gleak  = (const float*)d_in[13];
  const float* cmt    = (const float*)d_in[14];
  float* out = (float*)d_out;

  // d_ws layout: packed main params (256 KB) then packed sensory params (128 KB)
  float4* pp = (float4*)d_ws;
  float4* ps = pp + U * U;

  const int packN = U * U + I * U;  // 24576
  pack_params<<<(packN + 255) / 256, 256, 0, stream>>>(
      mu, sigma, W, erev, smu, ssig, sW, serev, pp, ps);
  ltc_kernel<<<B / M, BLK, 0, stream>>>(
      pp, ps, inputs, states, iw, ibias, vleak, gleak, cmt, out);
}